// Round 10
// baseline (151.843 us; speedup 1.0000x reference)
//
#include <hip/hip_runtime.h>
#include <hip/hip_bf16.h>
#include <stdint.h>

// ---------------------------------------------------------------------------
// GumbelQuantizer: z[32768,256] fp32, emb[1024,256] fp32 ->
//   out0 = softmax((-d + gumbel)) @ emb  (straight-through == quantized)
//   out1 = 1.25 * mean((quantized - z)^2)
// s_k = 2 z.e_k - |e_k|^2 (row-constant -|z|^2 cancels). Gumbel via exact JAX
// threefry2x32; e^g = rcp(-log2 u) (global 1/ln2 cancels in softmax).
//
// R10: LDS-diet restructure. R7 did 80 LDS ops/tile/wave (~43us LDS pipe,
// co-binding with 48us VALU). New shape: 1024 blocks x 32 z-rows, G0/G1
// interleaved even/odd (threefry pair rows adjacent -> same lane). m1 A-frags
// for rows 0-15 cached in 32 VGPRs for the WHOLE kernel (z constant across
// k-tiles); rows 16-31 in an 8KB LDS tile (8 reads/tile); P = 32x128 (8KB
// dbuf): m2 8 reads + 8 b16 stores. LDS ops 80 -> 16 per tile/wave. Price:
// E-tables read by 2x blocks (L2 0.5->1GB, VMEM pipe was idle). R7's proven
// region order kept: loads -> ciphers -> m1 | nb -> exp/store | barrier | m2.
// ---------------------------------------------------------------------------

typedef __bf16 bf16x8 __attribute__((ext_vector_type(8)));
typedef float  f32x4  __attribute__((ext_vector_type(4)));

#define MFMA16(A,B,C) __builtin_amdgcn_mfma_f32_16x16x32_bf16((A),(B),(C),0,0,0)

struct TF2 { uint32_t a, b; };

__host__ __device__ constexpr uint32_t rotl32(uint32_t v, int r){ return (v<<r)|(v>>(32-r)); }

// Threefry-2x32, 20 rounds — exact JAX implementation.
__host__ __device__ constexpr TF2 tf2x32(uint32_t k0, uint32_t k1, uint32_t x0, uint32_t x1){
  const uint32_t k2 = k0 ^ k1 ^ 0x1BD11BDAu;
  x0 += k0; x1 += k1;
  x0 += x1; x1 = rotl32(x1,13); x1 ^= x0;
  x0 += x1; x1 = rotl32(x1,15); x1 ^= x0;
  x0 += x1; x1 = rotl32(x1,26); x1 ^= x0;
  x0 += x1; x1 = rotl32(x1, 6); x1 ^= x0;
  x0 += k1; x1 += k2 + 1u;
  x0 += x1; x1 = rotl32(x1,17); x1 ^= x0;
  x0 += x1; x1 = rotl32(x1,29); x1 ^= x0;
  x0 += x1; x1 = rotl32(x1,16); x1 ^= x0;
  x0 += x1; x1 = rotl32(x1,24); x1 ^= x0;
  x0 += k2; x1 += k0 + 2u;
  x0 += x1; x1 = rotl32(x1,13); x1 ^= x0;
  x0 += x1; x1 = rotl32(x1,15); x1 ^= x0;
  x0 += x1; x1 = rotl32(x1,26); x1 ^= x0;
  x0 += x1; x1 = rotl32(x1, 6); x1 ^= x0;
  x0 += k0; x1 += k1 + 3u;
  x0 += x1; x1 = rotl32(x1,17); x1 ^= x0;
  x0 += x1; x1 = rotl32(x1,29); x1 ^= x0;
  x0 += x1; x1 = rotl32(x1,16); x1 ^= x0;
  x0 += x1; x1 = rotl32(x1,24); x1 ^= x0;
  x0 += k1; x1 += k2 + 4u;
  x0 += x1; x1 = rotl32(x1,13); x1 ^= x0;
  x0 += x1; x1 = rotl32(x1,15); x1 ^= x0;
  x0 += x1; x1 = rotl32(x1,26); x1 ^= x0;
  x0 += x1; x1 = rotl32(x1, 6); x1 ^= x0;
  x0 += k2; x1 += k0 + 5u;
  return {x0, x1};
}

// gkey = fold_in(key(0), 1) = threefry((0,0), (0,1)) — compile-time.
constexpr TF2 GKEY = tf2x32(0u, 0u, 0u, 1u);

__device__ __forceinline__ unsigned short f2bf(float f){
  __bf16 h = (__bf16)f;
  return __builtin_bit_cast(unsigned short, h);
}

// exp(gumbel) up to a global constant: 1/(-log2 u), u = JAX uniform(tiny,1)
__device__ __forceinline__ float gumbel_w(uint32_t bits){
  float uf = __uint_as_float((bits >> 9) | 0x3f800000u) - 1.0f;
  float u  = fmaxf(uf, 1.17549435e-38f);
  return __builtin_amdgcn_rcpf(-__log2f(u));
}

__device__ __forceinline__ bf16x8 pack8(float4 a, float4 b){
  bf16x8 r;
  r[0]=(__bf16)a.x; r[1]=(__bf16)a.y; r[2]=(__bf16)a.z; r[3]=(__bf16)a.w;
  r[4]=(__bf16)b.x; r[5]=(__bf16)b.y; r[6]=(__bf16)b.z; r[7]=(__bf16)b.w;
  return r;
}

// ---------------------------------------------------------------------------
// Prep: bf16 E [1024][256], bf16 E^T [256][1024], |e_k|^2 fp32 [1024]
// ---------------------------------------------------------------------------
__global__ void gq_prep(const float* __restrict__ emb, unsigned short* __restrict__ Eb,
                        unsigned short* __restrict__ ETb, float* __restrict__ enorm)
{
  const int r = blockIdx.x;       // 1024 emb rows
  const int t = threadIdx.x;      // 256 threads = one row
  float e = emb[r*256 + t];
  unsigned short h = f2bf(e);
  Eb[r*256 + t] = h;
  ETb[t*1024 + r] = h;
  float sq = e*e;
  #pragma unroll
  for (int o = 32; o > 0; o >>= 1) sq += __shfl_down(sq, o);
  __shared__ float ws4[4];
  if ((t & 63) == 0) ws4[t >> 6] = sq;
  __syncthreads();
  if (t == 0) enorm[r] = ws4[0] + ws4[1] + ws4[2] + ws4[3];
}

// ---------------------------------------------------------------------------
// Main: 1024 blocks x 512 threads (8 waves).
// Block b owns 32 "C-rows": C-row r <-> global z row g(r) = b*16 + (r>>1) +
// (r&1)*16384  (even rows = G0 t, odd = G1 t+16384 -> threefry pairs are
// lane-local: C layout gives lane hi rows 4hi..4hi+3 = 2 adjacent pairs).
// Rows 0-15: m1 A-fragments cached in registers (azc[8], whole kernel).
// Rows 16-31: bf16 in 8KB LDS tile zb.
// P = [32][128] bf16, XOR-swizzled, double-buffered (2 x 8KB).
// Per k-tile: wave w owns k-stripe [w*16,+16) (m1/gumbel) and d-cols
// [w*32,+32) (m2).
// ---------------------------------------------------------------------------
__global__ __launch_bounds__(512, 2)   // 128-VGPR budget (R7 lesson)
void gq_main(
    const float* __restrict__ z, const unsigned short* __restrict__ Eb,
    const unsigned short* __restrict__ ETb, const float* __restrict__ enorm,
    float* __restrict__ out, float* __restrict__ partials)
{
  __shared__ __align__(16) unsigned char sm[8192 + 16384];
  unsigned char* zb  = sm;                             // rows 16-31, swizzled
  unsigned char* Pl0 = sm + 8192;                      // P dbuf, swizzled
  float* denomW = (float*)(sm + 8192);                 // reuse P: [8][32]
  float* denomF = (float*)(sm + 8192 + 1024);          // [32]
  float* lsumW  = (float*)(sm + 8192 + 1024 + 128);    // [8]

  const int tid  = threadIdx.x;
  const int lane = tid & 63;
  const int wv   = tid >> 6;        // wave 0..7
  const int col  = lane & 15;
  const int hi   = lane >> 4;       // 0..3
  const int b16g = blockIdx.x * 16; // G0 row base

  // ---- stage C-rows 16..31 -> zb (bf16, swizzled); 1 b128 write/thread ----
  {
    int rp = tid >> 5;              // 0..15 (zb-local row)
    int c8 = tid & 31;              // float8 chunk
    int grow = b16g + 8 + (rp >> 1) + (rp & 1) * 16384;
    const float4* src = reinterpret_cast<const float4*>(z + (size_t)grow*256 + c8*8);
    float4 v0 = src[0], v1 = src[1];
    uint32_t w0 = (uint32_t)f2bf(v0.x) | ((uint32_t)f2bf(v0.y) << 16);
    uint32_t w1 = (uint32_t)f2bf(v0.z) | ((uint32_t)f2bf(v0.w) << 16);
    uint32_t w2 = (uint32_t)f2bf(v1.x) | ((uint32_t)f2bf(v1.y) << 16);
    uint32_t w3 = (uint32_t)f2bf(v1.z) | ((uint32_t)f2bf(v1.w) << 16);
    int boff = (rp*512 + c8*16) ^ ((rp & 7) << 4);
    uint32_t* p = reinterpret_cast<uint32_t*>(zb + boff);
    p[0] = w0; p[1] = w1; p[2] = w2; p[3] = w3;
  }

  // ---- cache m1 A-fragments for C-rows 0..15 in registers (persistent) ----
  // A-operand: row = lane&15, d-slice = hi*8 + kk*32.
  bf16x8 azc[8];
  {
    int growA = b16g + (col >> 1) + (col & 1) * 16384;
    const float* base = z + (size_t)growA*256 + hi*8;
    #pragma unroll
    for (int kk = 0; kk < 8; ++kk) {
      float4 a0 = *reinterpret_cast<const float4*>(base + kk*32);
      float4 a1 = *reinterpret_cast<const float4*>(base + kk*32 + 4);
      azc[kk] = pack8(a0, a1);
    }
  }
  __syncthreads();

  f32x4 accQ[2][2] = {};      // 2 row-tiles x 2 d-col-tiles
  float dn[2][4] = {};        // denominator partials
  float lsum = 0.0f;

  #pragma unroll 1
  for (int kt = 0; kt < 8; ++kt) {
    const int ke0 = kt*128 + wv*16;     // this wave's k-stripe base
    unsigned char* Pl = Pl0 + (kt & 1)*8192;

    // ---- region 1: mb loads + enorm + ciphers + m1 MFMAs ----
    const unsigned short* ebase = Eb + (size_t)(ke0 + col)*256 + hi*8;
    bf16x8 mb[8];
    #pragma unroll
    for (int kk = 0; kk < 8; ++kk)
      mb[kk] = *reinterpret_cast<const bf16x8*>(ebase + kk*32);

    float enk = enorm[ke0 + col];

    TF2 c[2][2];                // (row-tile, pair): rows 4hi+2p (G0), +1 (G1)
    #pragma unroll
    for (int rt = 0; rt < 2; ++rt) {
      #pragma unroll
      for (int p = 0; p < 2; ++p) {
        uint32_t t0 = (uint32_t)(b16g + rt*8 + 2*hi + p);
        uint32_t idx = t0*1024u + (uint32_t)(ke0 + col);
        c[rt][p] = tf2x32(GKEY.a, GKEY.b, idx, idx + (1u<<24));
      }
    }

    f32x4 aS[2] = {};
    __builtin_amdgcn_s_setprio(1);
    #pragma unroll
    for (int kk = 0; kk < 8; ++kk) {
      int aoff = (col*512 + kk*64 + hi*16) ^ ((col & 7) << 4);
      bf16x8 af1 = *reinterpret_cast<const bf16x8*>(zb + aoff);
      aS[0] = MFMA16(azc[kk], mb[kk], aS[0]);     // rows 0-15 from regs
      aS[1] = MFMA16(af1,     mb[kk], aS[1]);     // rows 16-31 from LDS
    }
    __builtin_amdgcn_s_setprio(0);

    // ---- region 2: nb loads + exp/gumbel/store-P ----
    const unsigned short* etb0 = ETb + (size_t)(wv*32 + col)*1024 + kt*128 + hi*8;
    const unsigned short* etb1 = etb0 + 16*1024;
    bf16x8 nb[8];
    #pragma unroll
    for (int kk = 0; kk < 4; ++kk) {
      nb[kk]   = *reinterpret_cast<const bf16x8*>(etb0 + kk*32);
      nb[kk+4] = *reinterpret_cast<const bf16x8*>(etb1 + kk*32);
    }

    int kl2 = (wv*16 + col)*2;         // P byte-col
    #pragma unroll
    for (int rt = 0; rt < 2; ++rt) {
      #pragma unroll
      for (int rg = 0; rg < 4; ++rg) {
        int row = rt*16 + hi*4 + rg;
        uint32_t bits = (rg & 1) ? c[rt][rg>>1].b : c[rt][rg>>1].a;
        float pv = __expf(2.0f*aS[rt][rg] - enk) * gumbel_w(bits);
        dn[rt][rg] += pv;
        *(unsigned short*)(Pl + ((row*256 + kl2) ^ ((row & 7) << 4))) = f2bf(pv);
      }
    }
    __syncthreads();

    // ---- region 3: m2 MFMAs (P from LDS, 8 reads) ----
    __builtin_amdgcn_s_setprio(1);
    #pragma unroll
    for (int kk = 0; kk < 4; ++kk) {
      #pragma unroll
      for (int rt = 0; rt < 2; ++rt) {
        int prow = rt*16 + col;
        int poff = (prow*256 + kk*64 + hi*16) ^ ((prow & 7) << 4);
        bf16x8 af = *reinterpret_cast<const bf16x8*>(Pl + poff);
        accQ[rt][0] = MFMA16(af, nb[kk],   accQ[rt][0]);
        accQ[rt][1] = MFMA16(af, nb[kk+4], accQ[rt][1]);
      }
    }
    __builtin_amdgcn_s_setprio(0);
    // no second barrier: next iteration writes the other P buffer
  }
  __syncthreads();   // protect reduction-scratch reuse of Pl

  // ---- denominator: reduce over 16 col-lanes, then 8 waves via LDS ----
  #pragma unroll
  for (int rt = 0; rt < 2; ++rt)
    #pragma unroll
    for (int rg = 0; rg < 4; ++rg) {
      float v = dn[rt][rg];
      v += __shfl_xor(v, 1);
      v += __shfl_xor(v, 2);
      v += __shfl_xor(v, 4);
      v += __shfl_xor(v, 8);
      dn[rt][rg] = v;
    }
  if (col == 0) {
    #pragma unroll
    for (int rt = 0; rt < 2; ++rt)
      #pragma unroll
      for (int rg = 0; rg < 4; ++rg)
        denomW[wv*32 + rt*16 + hi*4 + rg] = dn[rt][rg];
  }
  __syncthreads();
  if (tid < 32) {
    float s = 0.f;
    #pragma unroll
    for (int w2 = 0; w2 < 8; ++w2) s += denomW[w2*32 + tid];
    denomF[tid] = __builtin_amdgcn_rcpf(s);
  }
  __syncthreads();

  // ---- epilogue: normalize, write out0, loss partial ----
  #pragma unroll
  for (int rt = 0; rt < 2; ++rt) {
    #pragma unroll
    for (int rg = 0; rg < 4; ++rg) {
      int row = rt*16 + hi*4 + rg;
      float rd = denomF[row];
      int grow = b16g + (row >> 1) + (row & 1)*16384;
      float* orow = out + (size_t)grow*256;
      const float* zrow = z + (size_t)grow*256;
      #pragma unroll
      for (int ct = 0; ct < 2; ++ct) {
        int d = wv*32 + ct*16 + col;
        float q  = accQ[rt][ct][rg] * rd;
        float zv = zrow[d];
        float df = q - zv;
        orow[d] = zv + df;          // straight-through value == quantized
        lsum += df*df;
      }
    }
  }
  #pragma unroll
  for (int o = 32; o > 0; o >>= 1) lsum += __shfl_down(lsum, o);
  if (lane == 0) lsumW[wv] = lsum;
  __syncthreads();
  if (tid == 0) {
    float s = 0.f;
    #pragma unroll
    for (int w2 = 0; w2 < 8; ++w2) s += lsumW[w2];
    partials[blockIdx.x] = s;
  }
}

// ---------------------------------------------------------------------------
// Final: loss = 1.25 * sum(partials[0..1024)) / 2^23
// ---------------------------------------------------------------------------
__global__ void gq_final(const float* __restrict__ partials, float* __restrict__ out)
{
  const int t = threadIdx.x;   // 512
  float v = partials[t] + partials[t + 512];
  #pragma unroll
  for (int o = 32; o > 0; o >>= 1) v += __shfl_down(v, o);
  __shared__ float ws8[8];
  if ((t & 63) == 0) ws8[t >> 6] = v;
  __syncthreads();
  if (t == 0) {
    float s = 0.f;
    #pragma unroll
    for (int i = 0; i < 8; ++i) s += ws8[i];
    out[8388608] = 1.25f * s * (1.0f / 8388608.0f);
  }
}

extern "C" void kernel_launch(void* const* d_in, const int* in_sizes, int n_in,
                              void* d_out, int out_size, void* d_ws, size_t ws_size,
                              hipStream_t stream)
{
  const float* z   = (const float*)d_in[0];   // [32,1024,256]
  const float* emb = (const float*)d_in[1];   // [1024,256]
  float* out = (float*)d_out;                 // 8388608 + 1
  char* ws = (char*)d_ws;
  unsigned short* Eb  = (unsigned short*)ws;               // 524288 B
  unsigned short* ETb = (unsigned short*)(ws + 524288);    // 524288 B
  float* enorm    = (float*)(ws + 1048576);                // 4096 B
  float* partials = (float*)(ws + 1048576 + 4096);         // 4096 B

  gq_prep<<<1024, 256, 0, stream>>>(emb, Eb, ETb, enorm);
  gq_main<<<1024, 512, 0, stream>>>(z, Eb, ETb, enorm, out, partials);
  gq_final<<<1, 512, 0, stream>>>(partials, out);
}